// Round 15
// baseline (527.417 us; speedup 1.0000x reference)
//
#include <hip/hip_runtime.h>
#include <hip/hip_bf16.h>

// ---------- types / helpers ----------
typedef short short8 __attribute__((ext_vector_type(8)));
typedef short short4v __attribute__((ext_vector_type(4)));
typedef float f32x4 __attribute__((ext_vector_type(4)));

__device__ __forceinline__ float bf2f(short s) {
  return __builtin_bit_cast(float, (unsigned)((unsigned short)s) << 16);
}
__device__ __forceinline__ short f2bf(float f) {
  return __builtin_bit_cast(short, __float2bfloat16(f));
}
__device__ __forceinline__ void g2lds16(const void* g, void* l) {
  __builtin_amdgcn_global_load_lds((const __attribute__((address_space(1))) void*)g,
                                   (__attribute__((address_space(3))) void*)l, 16, 0, 0);
}

// ---------- dims ----------
// B=2048, CIN=1024, L=30
// conv1: M=61440 N=512 K=3072 ; conv2: M=32768 N=256 K=1536
// fc: M=2048 N=1024 K=2304 ; experts dense: M=2048 N=4096 K=1024

// ---------- prep: x [B,1024,30] f32 -> xt [B,32,1024] bf16 (rows 0,31 zero) ----------
__global__ __launch_bounds__(256) void prep_x(const float* __restrict__ x, short* __restrict__ xt) {
  __shared__ float tile[64 * 30];
  const int b = blockIdx.x, ci0 = blockIdx.y * 64, t = threadIdx.x;
  const float* src = x + ((long)b * 1024 + ci0) * 30;
  for (int i = t; i < 480; i += 256)
    ((float4*)tile)[i] = ((const float4*)src)[i];
  __syncthreads();
  short* dst = xt + (long)b * 32 * 1024 + ci0;
  // 32 lp x 16 ci-quads = 512 short4 items
  for (int i = t; i < 512; i += 256) {
    int lp = i >> 4, cq = i & 15;
    short4v v = {0, 0, 0, 0};
    if (lp >= 1 && lp <= 30) {
#pragma unroll
      for (int u = 0; u < 4; ++u) v[u] = f2bf(tile[(cq * 4 + u) * 30 + lp - 1]);
    }
    *(short4v*)&dst[(long)lp * 1024 + cq * 4] = v;
  }
}

// ---------- prep: all weight transforms (bf16 casts / permutes) ----------
__global__ __launch_bounds__(256) void prep_weights(
    const float* __restrict__ conv1_w, const float* __restrict__ conv2_w,
    const float* __restrict__ fc_w, const float* __restrict__ e_w1,
    const float* __restrict__ fin_w,
    short* __restrict__ w1t, short* __restrict__ w2t, short* __restrict__ fcwt,
    short* __restrict__ ew1t, float* __restrict__ finw1, float* __restrict__ finw2) {
  const int T0 = 1572864;            // w1t  [512][3072]  (k-major: j = k*1024+ci)
  const int T1 = T0 + 393216;        // w2t  [256][1536]  (j = k*512+ci)
  const int T2 = T1 + 2359296;       // fcwt [1024][2304] (j = jj*256+co)
  const int T3 = T2 + 4194304;       // ew1t [4096][1024] straight cast
  const int T4 = T3 + 30720;         // finw1 [2][15360]  (i = l*512+co)
  const int T5 = T4 + 8192;          // finw2 [2][4096]   (i = l*256+co)
  for (long idx = (long)blockIdx.x * 256 + threadIdx.x; idx < T5;
       idx += (long)gridDim.x * 256) {
    if (idx < T0) {
      int i = (int)idx; int co = i / 3072, j = i % 3072, k = j >> 10, ci = j & 1023;
      w1t[i] = f2bf(conv1_w[(co * 1024 + ci) * 3 + k]);
    } else if (idx < T1) {
      int i = (int)(idx - T0); int co = i / 1536, j = i % 1536, k = j >> 9, ci = j & 511;
      w2t[i] = f2bf(conv2_w[(co * 512 + ci) * 3 + k]);
    } else if (idx < T2) {
      int i = (int)(idx - T1); int n = i / 2304, j = i % 2304, jj = j >> 8, co = j & 255;
      fcwt[i] = f2bf(fc_w[n * 2304 + co * 9 + jj]);
    } else if (idx < T3) {
      int i = (int)(idx - T2);
      ew1t[i] = f2bf(e_w1[i]);
    } else if (idx < T4) {
      int i = (int)(idx - T3); int c = i / 15360, r = i % 15360, l = r >> 9, co = r & 511;
      finw1[i] = fin_w[c * 19458 + 2 + co * 30 + l];
    } else {
      int i = (int)(idx - T4); int c = i / 4096, r = i % 4096, l = r >> 8, co = r & 255;
      finw2[i] = fin_w[c * 19458 + 2 + 15360 + co * 16 + l];
    }
  }
}

// ---------- 256x256 8-wave BK=64 dbuf GEMM (conv1): A via LDS, B direct from L2 ----------
// Round-7 proven barrier skeleton. B fragments load straight from global
// (w1t = 3MB, L2-resident) into registers — removes 1/3 of LDS reads and
// 1/2 of LDS writes (LDS was the per-tile long pole: 256KB -> 160KB).
// CRITICAL ordering (round-9 lesson): LOADB(cur) is issued BEFORE
// STAGEA(next) so the first B use waits vmcnt(4) (A-prefetch stays in
// flight), not vmcnt(0). sched_barrier(0) pins that order.
__global__ __launch_bounds__(512, 2) void gemm256_bt_relu(
    const short* __restrict__ A, const short* __restrict__ Bm, short* __restrict__ C,
    const float* __restrict__ bias, int N, int K, int L, int S1, int S2, int nNB) {
  __shared__ __align__(16) short lA0[256 * 64], lA1[256 * 64];
  const int t = threadIdx.x, wave = t >> 6, lane = t & 63;
  const int wr = wave >> 2, wc = wave & 3;
  const int nwg = gridDim.x, qn = nwg >> 3, bid = blockIdx.x;
  const int swz = (bid & 7) * qn + (bid >> 3);
  const int m0 = (swz / nNB) * 256, n0 = (swz % nNB) * 256;
  const int srow = t >> 3;                       // staged row 0..63 (+q*64)
  const int scol = (((t & 7) ^ (srow & 7)) * 8); // pre-swizzled source col block

  long aoff[4];
#pragma unroll
  for (int q = 0; q < 4; ++q) {
    int m = m0 + q * 64 + srow;
    aoff[q] = (long)(m / L) * S1 + (long)(m % L) * S2 + scol;
  }
  const int ldst = wave * 512 + lane * 8;

  const int l7 = lane & 7, g4 = lane >> 4, r16 = lane & 15;
  long brow[4];
#pragma unroll
  for (int j = 0; j < 4; ++j)
    brow[j] = (long)(n0 + wc * 64 + j * 16 + r16) * K + g4 * 8;

  f32x4 acc[8][4];
#pragma unroll
  for (int i = 0; i < 8; ++i)
#pragma unroll
    for (int j = 0; j < 4; ++j) acc[i][j] = f32x4{0.f, 0.f, 0.f, 0.f};

  const int nK = K >> 6;  // must be even
  short8 bfr[4][2];

#define STAGEA(k0, dA) do {                                           \
    const long kk0_ = (long)(k0);                                     \
    _Pragma("unroll")                                                 \
    for (int q = 0; q < 4; ++q)                                       \
      g2lds16(A + aoff[q] + kk0_, &dA[q * 4096 + ldst]);              \
    } while (0)

#define LOADB(k0) do {                                                \
    const long kb_ = (long)(k0);                                      \
    _Pragma("unroll") for (int j = 0; j < 4; ++j)                     \
    _Pragma("unroll") for (int kk = 0; kk < 2; ++kk)                  \
      bfr[j][kk] = *(const short8*)&Bm[brow[j] + kb_ + kk * 32];      \
    __builtin_amdgcn_sched_barrier(0);                                \
    } while (0)

#define PHASESB(sA) do {                                                              \
    short8 af[4][2];                                                                  \
    /* phase 0: read A lo; MFMA i0-3 x j0-1 */                                        \
    _Pragma("unroll") for (int kk = 0; kk < 2; ++kk) {                                \
      const int jb = ((kk * 4 + g4) ^ l7) * 8;                                        \
      _Pragma("unroll") for (int i = 0; i < 4; ++i)                                   \
        af[i][kk] = *(const short8*)&sA[(wr * 128 + i * 16 + r16) * 64 + jb];         \
    }                                                                                 \
    __builtin_amdgcn_s_setprio(1);                                                    \
    _Pragma("unroll") for (int i = 0; i < 4; ++i)                                     \
    _Pragma("unroll") for (int j = 0; j < 2; ++j)                                     \
    _Pragma("unroll") for (int kk = 0; kk < 2; ++kk)                                  \
      acc[i][j] = __builtin_amdgcn_mfma_f32_16x16x32_bf16(af[i][kk], bfr[j][kk], acc[i][j], 0, 0, 0); \
    __builtin_amdgcn_s_setprio(0);                                                    \
    /* phase 1: MFMA i0-3 x j2-3 */                                                   \
    __builtin_amdgcn_s_setprio(1);                                                    \
    _Pragma("unroll") for (int i = 0; i < 4; ++i)                                     \
    _Pragma("unroll") for (int j = 0; j < 2; ++j)                                     \
    _Pragma("unroll") for (int kk = 0; kk < 2; ++kk)                                  \
      acc[i][2 + j] = __builtin_amdgcn_mfma_f32_16x16x32_bf16(af[i][kk], bfr[2 + j][kk], acc[i][2 + j], 0, 0, 0); \
    __builtin_amdgcn_s_setprio(0);                                                    \
    /* phase 2: read A hi; MFMA i4-7 x j2-3 */                                        \
    _Pragma("unroll") for (int kk = 0; kk < 2; ++kk) {                                \
      const int jb = ((kk * 4 + g4) ^ l7) * 8;                                        \
      _Pragma("unroll") for (int i = 0; i < 4; ++i)                                   \
        af[i][kk] = *(const short8*)&sA[(wr * 128 + (4 + i) * 16 + r16) * 64 + jb];   \
    }                                                                                 \
    __builtin_amdgcn_s_setprio(1);                                                    \
    _Pragma("unroll") for (int i = 0; i < 4; ++i)                                     \
    _Pragma("unroll") for (int j = 0; j < 2; ++j)                                     \
    _Pragma("unroll") for (int kk = 0; kk < 2; ++kk)                                  \
      acc[4 + i][2 + j] = __builtin_amdgcn_mfma_f32_16x16x32_bf16(af[i][kk], bfr[2 + j][kk], acc[4 + i][2 + j], 0, 0, 0); \
    __builtin_amdgcn_s_setprio(0);                                                    \
    /* phase 3: MFMA i4-7 x j0-1 */                                                   \
    __builtin_amdgcn_s_setprio(1);                                                    \
    _Pragma("unroll") for (int i = 0; i < 4; ++i)                                     \
    _Pragma("unroll") for (int j = 0; j < 2; ++j)                                     \
    _Pragma("unroll") for (int kk = 0; kk < 2; ++kk)                                  \
      acc[4 + i][j] = __builtin_amdgcn_mfma_f32_16x16x32_bf16(af[i][kk], bfr[j][kk], acc[4 + i][j], 0, 0, 0); \
    __builtin_amdgcn_s_setprio(0);                                                    \
  } while (0)

  STAGEA(0, lA0);
  for (int ktp = 0; ktp < (nK >> 1); ++ktp) {
    const int t1 = 2 * ktp + 1;
    __syncthreads();                      // lA0 (even tile) published; drain covered
    LOADB((long)(2 * ktp) << 6);          // B frags for even tile (L2), BEFORE prefetch
    STAGEA((long)t1 << 6, lA1);           // prefetch odd A-tile
    PHASESB(lA0);                         // compute even tile (B-wait = vmcnt(4))
    __syncthreads();                      // lA1 (odd) published
    LOADB((long)t1 << 6);
    if (t1 + 1 < nK) STAGEA((long)(t1 + 1) << 6, lA0);
    PHASESB(lA1);                         // compute odd tile
  }

#pragma unroll
  for (int j = 0; j < 4; ++j) {
    int col = n0 + wc * 64 + j * 16 + r16;
    float bv = bias[col];
#pragma unroll
    for (int i = 0; i < 8; ++i) {
      int rbase = m0 + wr * 128 + i * 16 + (g4 << 2);
#pragma unroll
      for (int r = 0; r < 4; ++r) {
        float o = fmaxf(acc[i][j][r] + bv, 0.f);
        C[(long)(rbase + r) * N + col] = f2bf(o);
      }
    }
  }
#undef STAGEA
#undef LOADB
#undef PHASESB
}

// ---------- 128x128 4-wave BK=64 static-dbuf GEMM (conv2 / fc / experts) ----------
__global__ __launch_bounds__(256, 2) void gemm128_bt_relu(
    const short* __restrict__ A, const short* __restrict__ Bm, short* __restrict__ C,
    const float* __restrict__ bias, int N, int K, int L, int S1, int S2, int nNB) {
  __shared__ __align__(16) short lA0[128 * 64], lA1[128 * 64];
  __shared__ __align__(16) short lB0[128 * 64], lB1[128 * 64];
  const int t = threadIdx.x, wave = t >> 6, lane = t & 63;
  const int wr = wave >> 1, wc = wave & 1;
  const int nwg = gridDim.x, qn = nwg >> 3, bid = blockIdx.x;
  const int swz = (bid & 7) * qn + (bid >> 3);
  const int m0 = (swz / nNB) * 128, n0 = (swz % nNB) * 128;
  const int arow = t >> 3;
  const int acolg = (((t & 7) ^ (arow & 7)) * 8);

  long aoff[4], boff[4];
#pragma unroll
  for (int qq = 0; qq < 4; ++qq) {
    int m = m0 + qq * 32 + arow;
    aoff[qq] = (long)(m / L) * S1 + (long)(m % L) * S2 + acolg;
    boff[qq] = (long)(n0 + qq * 32 + arow) * K + acolg;
  }
  const int ldst = wave * 512 + lane * 8;

  f32x4 acc[4][4];
#pragma unroll
  for (int i = 0; i < 4; ++i)
#pragma unroll
    for (int j = 0; j < 4; ++j) acc[i][j] = f32x4{0.f, 0.f, 0.f, 0.f};

  const int l7 = lane & 7, g4 = lane >> 4, r16 = lane & 15;
  const int nK = K >> 6;  // 24 / 36 / 16 here — all even

#define STAGE128(k0, dA, dB) do {                                     \
    const long kk0_ = (long)(k0);                                     \
    _Pragma("unroll")                                                 \
    for (int qq = 0; qq < 4; ++qq) {                                  \
      g2lds16(A + aoff[qq] + kk0_, &dA[qq * 2048 + ldst]);            \
      g2lds16(Bm + boff[qq] + kk0_, &dB[qq * 2048 + ldst]);           \
    } } while (0)

#define PHASES128(sA, sB) do {                                                        \
    _Pragma("unroll")                                                                 \
    for (int kk = 0; kk < 2; ++kk) {                                                  \
      const int jblk = ((kk * 4 + g4) ^ l7) * 8;                                      \
      short8 af[4], bfv[4];                                                           \
      _Pragma("unroll") for (int i = 0; i < 4; ++i)                                   \
        af[i] = *(const short8*)&sA[(wr * 64 + i * 16 + r16) * 64 + jblk];            \
      _Pragma("unroll") for (int j = 0; j < 4; ++j)                                   \
        bfv[j] = *(const short8*)&sB[(wc * 64 + j * 16 + r16) * 64 + jblk];           \
      __builtin_amdgcn_s_setprio(1);                                                  \
      _Pragma("unroll") for (int i = 0; i < 4; ++i)                                   \
      _Pragma("unroll") for (int j = 0; j < 4; ++j)                                   \
        acc[i][j] = __builtin_amdgcn_mfma_f32_16x16x32_bf16(af[i], bfv[j], acc[i][j], 0, 0, 0); \
      __builtin_amdgcn_s_setprio(0);                                                  \
    } } while (0)

  STAGE128(0, lA0, lB0);
  for (int ktp = 0; ktp < (nK >> 1); ++ktp) {
    const int t1 = 2 * ktp + 1;
    __syncthreads();                       // even tile ready (drain covered)
    STAGE128((long)t1 << 6, lA1, lB1);     // prefetch odd tile
    PHASES128(lA0, lB0);                   // compute even tile
    __syncthreads();                       // odd tile ready
    if (t1 + 1 < nK) STAGE128((long)(t1 + 1) << 6, lA0, lB0);
    PHASES128(lA1, lB1);                   // compute odd tile
  }

#pragma unroll
  for (int j = 0; j < 4; ++j) {
    int col = n0 + wc * 64 + j * 16 + r16;
    float bv = bias[col];
#pragma unroll
    for (int i = 0; i < 4; ++i) {
      int rbase = m0 + wr * 64 + i * 16 + (g4 << 2);
#pragma unroll
      for (int r = 0; r < 4; ++r) {
        float o = fmaxf(acc[i][j][r] + bv, 0.f);
        C[(long)(rbase + r) * N + col] = f2bf(o);
      }
    }
  }
#undef STAGE128
#undef PHASES128
}

// ---------- pool1 + fin-x1 dot (block per b): p1t + fin1p[b][2] ----------
__global__ __launch_bounds__(256) void pool1_fused(
    const short* __restrict__ x1t, short* __restrict__ p1t,
    const float* __restrict__ finw1, float* __restrict__ fin1p) {
  const int b = blockIdx.x, t = threadIdx.x, lane = t & 63, wave = t >> 6;
  const short* xb = x1t + (long)b * 15360;
  short* pb = p1t + (long)b * 9216;
  // pools: 18 x 128 short4 items
  for (int i = t; i < 2304; i += 256) {
    int c4 = i & 127, jp = i >> 7;
    short4v v = {0, 0, 0, 0};
    if (jp >= 1 && jp <= 16) {
      int j = jp - 1, l0 = 2 * j - 1, l1 = 2 * j;
      short4v a = (l0 >= 0) ? *(const short4v*)&xb[l0 * 512 + c4 * 4] : short4v{0, 0, 0, 0};
      short4v bb = (l1 < 30) ? *(const short4v*)&xb[l1 * 512 + c4 * 4] : short4v{0, 0, 0, 0};
#pragma unroll
      for (int u = 0; u < 4; ++u) v[u] = f2bf(fmaxf(bf2f(a[u]), bf2f(bb[u])));
    }
    *(short4v*)&pb[i * 4] = v;
  }
  // fin dot over x1t[b] (15360 elems), L2-hot
  float f0 = 0.f, f1 = 0.f;
#pragma unroll
  for (int it = 0; it < 15; ++it) {
    int i = (it * 256 + t) * 4;
    short4v xv = *(const short4v*)&xb[i];
    float4 w0 = *(const float4*)&finw1[i];
    float4 w1 = *(const float4*)&finw1[15360 + i];
    float a0 = bf2f(xv[0]), a1 = bf2f(xv[1]), a2 = bf2f(xv[2]), a3 = bf2f(xv[3]);
    f0 += a0 * w0.x + a1 * w0.y + a2 * w0.z + a3 * w0.w;
    f1 += a0 * w1.x + a1 * w1.y + a2 * w1.z + a3 * w1.w;
  }
#pragma unroll
  for (int off = 32; off > 0; off >>= 1) {
    f0 += __shfl_down(f0, off);
    f1 += __shfl_down(f1, off);
  }
  __shared__ float red[4][2];
  if (lane == 0) { red[wave][0] = f0; red[wave][1] = f1; }
  __syncthreads();
  if (t == 0) {
    float F0 = red[0][0] + red[1][0] + red[2][0] + red[3][0];
    float F1 = red[0][1] + red[1][1] + red[2][1] + red[3][1];
    fin1p[b * 2 + 0] = F0;
    fin1p[b * 2 + 1] = F1;
  }
}

// ---------- pool2 + fin-x2 dot (block per b): p2t + fin2p[b][2] ----------
__global__ __launch_bounds__(256) void pool2_fused(
    const short* __restrict__ x2t, short* __restrict__ p2t,
    const float* __restrict__ finw2, float* __restrict__ fin2p) {
  const int b = blockIdx.x, t = threadIdx.x, lane = t & 63, wave = t >> 6;
  const short* xb = x2t + (long)b * 4096;
  short* pb = p2t + (long)b * 2304;
  // pools: 9 x 64 short4 items
  for (int i = t; i < 576; i += 256) {
    int c4 = i & 63, j = i >> 6;
    int l0 = 2 * j - 1, l1 = 2 * j;
    short4v a = (l0 >= 0) ? *(const short4v*)&xb[l0 * 256 + c4 * 4] : short4v{0, 0, 0, 0};
    short4v bb = (l1 < 16) ? *(const short4v*)&xb[l1 * 256 + c4 * 4] : short4v{0, 0, 0, 0};
    short4v v;
#pragma unroll
    for (int u = 0; u < 4; ++u) v[u] = f2bf(fmaxf(bf2f(a[u]), bf2f(bb[u])));
    *(short4v*)&pb[i * 4] = v;
  }
  // fin dot over x2t[b] (4096 elems)
  float f0 = 0.f, f1 = 0.f;
#pragma unroll
  for (int it = 0; it < 4; ++it) {
    int i = (it * 256 + t) * 4;
    short4v xv = *(const short4v*)&xb[i];
    float4 w0 = *(const float4*)&finw2[i];
    float4 w1 = *(const float4*)&finw2[4096 + i];
    float a0 = bf2f(xv[0]), a1 = bf2f(xv[1]), a2 = bf2f(xv[2]), a3 = bf2f(xv[3]);
    f0 += a0 * w0.x + a1 * w0.y + a2 * w0.z + a3 * w0.w;
    f1 += a0 * w1.x + a1 * w1.y + a2 * w1.z + a3 * w1.w;
  }
#pragma unroll
  for (int off = 32; off > 0; off >>= 1) {
    f0 += __shfl_down(f0, off);
    f1 += __shfl_down(f1, off);
  }
  __shared__ float red[4][2];
  if (lane == 0) { red[wave][0] = f0; red[wave][1] = f1; }
  __syncthreads();
  if (t == 0) {
    fin2p[b * 2 + 0] = red[0][0] + red[1][0] + red[2][0] + red[3][0];
    fin2p[b * 2 + 1] = red[0][1] + red[1][1] + red[2][1] + red[3][1];
  }
}

// ---------- final (slim): expert select + agg fold + partials -> out [B,2] ----------
__global__ __launch_bounds__(64) void final_k(
    const short* __restrict__ h, const int* __restrict__ eidx,
    const float* __restrict__ e_w2, const float* __restrict__ e_b2,
    const float* __restrict__ agg_w, const float* __restrict__ agg_b,
    const float* __restrict__ fin_w, const float* __restrict__ fin_b,
    const float* __restrict__ fin1p, const float* __restrict__ fin2p,
    float* __restrict__ out) {
  const int b = blockIdx.x, lane = threadIdx.x;
  const int e = eidx[b];
  const short* hp = h + (long)b * 4096 + e * 512;
  const float* w20 = e_w2 + (e * 2 + 0) * 512;
  const float* w21 = e_w2 + (e * 2 + 1) * 512;
  float s0 = 0.f, s1 = 0.f;
#pragma unroll
  for (int it = 0; it < 8; ++it) {
    int i = it * 64 + lane;
    float hv = bf2f(hp[i]);
    s0 += hv * w20[i];
    s1 += hv * w21[i];
  }
#pragma unroll
  for (int off = 32; off > 0; off >>= 1) {
    s0 += __shfl_down(s0, off);
    s1 += __shfl_down(s1, off);
  }
  if (lane == 0) {
    float sel0 = s0 + e_b2[e * 2 + 0];
    float sel1 = s1 + e_b2[e * 2 + 1];
    float agg0 = sel0 * agg_w[e * 2] + sel1 * agg_w[e * 2 + 1] + agg_b[0];
    float agg1 = sel0 * agg_w[16 + e * 2] + sel1 * agg_w[16 + e * 2 + 1] + agg_b[1];
    float F0 = fin1p[b * 2 + 0] + fin2p[b * 2 + 0];
    float F1 = fin1p[b * 2 + 1] + fin2p[b * 2 + 1];
    out[b * 2 + 0] = F0 + agg0 * fin_w[0] + agg1 * fin_w[1] + fin_b[0];
    out[b * 2 + 1] = F1 + agg0 * fin_w[19458 + 0] + agg1 * fin_w[19458 + 1] + fin_b[1];
  }
}

// ---------- launch ----------
extern "C" void kernel_launch(void* const* d_in, const int* in_sizes, int n_in,
                              void* d_out, int out_size, void* d_ws, size_t ws_size,
                              hipStream_t stream) {
  const float* x       = (const float*)d_in[0];
  const int*   eidx    = (const int*)d_in[1];
  const float* conv1_w = (const float*)d_in[2];
  const float* conv1_b = (const float*)d_in[3];
  const float* conv2_w = (const float*)d_in[4];
  const float* conv2_b = (const float*)d_in[5];
  const float* fc_w    = (const float*)d_in[6];
  const float* fc_b    = (const float*)d_in[7];
  const float* e_w1    = (const float*)d_in[8];
  const float* e_b1    = (const float*)d_in[9];
  const float* e_w2    = (const float*)d_in[10];
  const float* e_b2    = (const float*)d_in[11];
  const float* agg_w   = (const float*)d_in[12];
  const float* agg_b   = (const float*)d_in[13];
  const float* fin_w   = (const float*)d_in[14];
  const float* fin_b   = (const float*)d_in[15];
  float* out = (float*)d_out;

  char* ws = (char*)d_ws;
  short* xt    = (short*)(ws + 0L);          // 134,217,728
  short* x1t   = (short*)(ws + 134217728L);  //  62,914,560
  short* p1t   = (short*)(ws + 197132288L);  //  37,748,736
  short* x2t   = (short*)(ws + 234881024L);  //  16,777,216
  short* p2t   = (short*)(ws + 251658240L);  //   9,437,184
  short* sf    = (short*)(ws + 261095424L);  //   4,194,304
  short* h     = (short*)(ws + 265289728L);  //  16,777,216
  short* w1t   = (short*)(ws + 282066944L);  //   3,145,728
  short* w2t   = (short*)(ws + 285212672L);  //     786,432
  short* fcwt  = (short*)(ws + 285999104L);  //   4,718,592
  short* ew1t  = (short*)(ws + 290717696L);  //   8,388,608
  float* finw1 = (float*)(ws + 299106304L);  //     122,880
  float* finw2 = (float*)(ws + 299229184L);  //      32,768  -> total 299,261,952 B
  // fin partials alias the xt region (xt dead after conv1; pools run later)
  float* fin1p = (float*)(ws + 0L);          //      16,384
  float* fin2p = (float*)(ws + 16384L);      //      16,384

  prep_weights<<<4096, 256, 0, stream>>>(conv1_w, conv2_w, fc_w, e_w1, fin_w,
                                         w1t, w2t, fcwt, ew1t, finw1, finw2);
  prep_x<<<dim3(2048, 16), 256, 0, stream>>>(x, xt);
  // conv1: M=61440 N=512 K=3072; 256^2 tiles -> grid 240m x 2n = 480 (480%8==0)
  gemm256_bt_relu<<<480, 512, 0, stream>>>(xt, w1t, x1t, conv1_b, 512, 3072, 30, 32768, 1024, 2);
  pool1_fused<<<2048, 256, 0, stream>>>(x1t, p1t, finw1, fin1p);
  // conv2: M=32768 N=256 K=1536, rows = p1t[(b*18+j)*512]; grid 256m x 2n = 512
  gemm128_bt_relu<<<512, 256, 0, stream>>>(p1t, w2t, x2t, conv2_b, 256, 1536, 16, 9216, 512, 2);
  pool2_fused<<<2048, 256, 0, stream>>>(x2t, p2t, finw2, fin2p);
  // fc: M=2048 N=1024 K=2304; grid 16m x 8n = 128
  gemm128_bt_relu<<<128, 256, 0, stream>>>(p2t, fcwt, sf, fc_b, 1024, 2304, 1, 2304, 0, 8);
  // experts dense: M=2048 N=4096 K=1024; grid 16m x 32n = 512
  gemm128_bt_relu<<<512, 256, 0, stream>>>(sf, ew1t, h, e_b1, 4096, 1024, 1, 1024, 0, 32);
  final_k<<<2048, 64, 0, stream>>>(h, eidx, e_w2, e_b2, agg_w, agg_b,
                                   fin_w, fin_b, fin1p, fin2p, out);
}

// Round 16
// 395.681 us; speedup vs baseline: 1.3329x; 1.3329x over previous
//
#include <hip/hip_runtime.h>
#include <hip/hip_bf16.h>

// ---------- types / helpers ----------
typedef short short8 __attribute__((ext_vector_type(8)));
typedef short short4v __attribute__((ext_vector_type(4)));
typedef float f32x4 __attribute__((ext_vector_type(4)));

__device__ __forceinline__ float bf2f(short s) {
  return __builtin_bit_cast(float, (unsigned)((unsigned short)s) << 16);
}
__device__ __forceinline__ short f2bf(float f) {
  return __builtin_bit_cast(short, __float2bfloat16(f));
}
__device__ __forceinline__ void g2lds16(const void* g, void* l) {
  __builtin_amdgcn_global_load_lds((const __attribute__((address_space(1))) void*)g,
                                   (__attribute__((address_space(3))) void*)l, 16, 0, 0);
}

// ---------- dims ----------
// B=2048, CIN=1024, L=30
// conv1: M=61440 N=512 K=3072 ; conv2: M=32768 N=256 K=1536
// fc: M=2048 N=1024 K=2304 ; experts dense: M=2048 N=4096 K=1024

// ---------- prep: x [B,1024,30] f32 -> xt [B,32,1024] bf16 (rows 0,31 zero) ----------
__global__ __launch_bounds__(256) void prep_x(const float* __restrict__ x, short* __restrict__ xt) {
  __shared__ float tile[64 * 30];
  const int b = blockIdx.x, ci0 = blockIdx.y * 64, t = threadIdx.x;
  const float* src = x + ((long)b * 1024 + ci0) * 30;
  for (int i = t; i < 480; i += 256)
    ((float4*)tile)[i] = ((const float4*)src)[i];
  __syncthreads();
  short* dst = xt + (long)b * 32 * 1024 + ci0;
  // 32 lp x 16 ci-quads = 512 short4 items
  for (int i = t; i < 512; i += 256) {
    int lp = i >> 4, cq = i & 15;
    short4v v = {0, 0, 0, 0};
    if (lp >= 1 && lp <= 30) {
#pragma unroll
      for (int u = 0; u < 4; ++u) v[u] = f2bf(tile[(cq * 4 + u) * 30 + lp - 1]);
    }
    *(short4v*)&dst[(long)lp * 1024 + cq * 4] = v;
  }
}

// ---------- prep: all weight transforms (bf16 casts / permutes) ----------
__global__ __launch_bounds__(256) void prep_weights(
    const float* __restrict__ conv1_w, const float* __restrict__ conv2_w,
    const float* __restrict__ fc_w, const float* __restrict__ e_w1,
    const float* __restrict__ fin_w,
    short* __restrict__ w1t, short* __restrict__ w2t, short* __restrict__ fcwt,
    short* __restrict__ ew1t, float* __restrict__ finw1, float* __restrict__ finw2) {
  const int T0 = 1572864;            // w1t  [512][3072]  (k-major: j = k*1024+ci)
  const int T1 = T0 + 393216;        // w2t  [256][1536]  (j = k*512+ci)
  const int T2 = T1 + 2359296;       // fcwt [1024][2304] (j = jj*256+co)
  const int T3 = T2 + 4194304;       // ew1t [4096][1024] straight cast
  const int T4 = T3 + 30720;         // finw1 [2][15360]  (i = l*512+co)
  const int T5 = T4 + 8192;          // finw2 [2][4096]   (i = l*256+co)
  for (long idx = (long)blockIdx.x * 256 + threadIdx.x; idx < T5;
       idx += (long)gridDim.x * 256) {
    if (idx < T0) {
      int i = (int)idx; int co = i / 3072, j = i % 3072, k = j >> 10, ci = j & 1023;
      w1t[i] = f2bf(conv1_w[(co * 1024 + ci) * 3 + k]);
    } else if (idx < T1) {
      int i = (int)(idx - T0); int co = i / 1536, j = i % 1536, k = j >> 9, ci = j & 511;
      w2t[i] = f2bf(conv2_w[(co * 512 + ci) * 3 + k]);
    } else if (idx < T2) {
      int i = (int)(idx - T1); int n = i / 2304, j = i % 2304, jj = j >> 8, co = j & 255;
      fcwt[i] = f2bf(fc_w[n * 2304 + co * 9 + jj]);
    } else if (idx < T3) {
      int i = (int)(idx - T2);
      ew1t[i] = f2bf(e_w1[i]);
    } else if (idx < T4) {
      int i = (int)(idx - T3); int c = i / 15360, r = i % 15360, l = r >> 9, co = r & 511;
      finw1[i] = fin_w[c * 19458 + 2 + co * 30 + l];
    } else {
      int i = (int)(idx - T4); int c = i / 4096, r = i % 4096, l = r >> 8, co = r & 255;
      finw2[i] = fin_w[c * 19458 + 2 + 15360 + co * 16 + l];
    }
  }
}

// ---------- 256x256 8-wave BK=64 static-dbuf GEMM (conv1) — round-7/12 proven ----------
__global__ __launch_bounds__(512, 2) void gemm256_bt_relu(
    const short* __restrict__ A, const short* __restrict__ Bm, short* __restrict__ C,
    const float* __restrict__ bias, int N, int K, int L, int S1, int S2, int nNB) {
  __shared__ __align__(16) short lA0[256 * 64], lA1[256 * 64];
  __shared__ __align__(16) short lB0[256 * 64], lB1[256 * 64];
  const int t = threadIdx.x, wave = t >> 6, lane = t & 63;
  const int wr = wave >> 2, wc = wave & 3;
  const int nwg = gridDim.x, qn = nwg >> 3, bid = blockIdx.x;
  const int swz = (bid & 7) * qn + (bid >> 3);
  const int m0 = (swz / nNB) * 256, n0 = (swz % nNB) * 256;
  const int srow = t >> 3;                       // staged row 0..63 (+q*64)
  const int scol = (((t & 7) ^ (srow & 7)) * 8); // pre-swizzled source col block

  long aoff[4], boff[4];
#pragma unroll
  for (int q = 0; q < 4; ++q) {
    int m = m0 + q * 64 + srow;
    aoff[q] = (long)(m / L) * S1 + (long)(m % L) * S2 + scol;
    boff[q] = (long)(n0 + q * 64 + srow) * K + scol;
  }
  const int ldst = wave * 512 + lane * 8;

  f32x4 acc[8][4];
#pragma unroll
  for (int i = 0; i < 8; ++i)
#pragma unroll
    for (int j = 0; j < 4; ++j) acc[i][j] = f32x4{0.f, 0.f, 0.f, 0.f};

  const int l7 = lane & 7, g4 = lane >> 4, r16 = lane & 15;
  const int nK = K >> 6;  // must be even

#define STAGE256(k0, dA, dB) do {                                     \
    const long kk0_ = (long)(k0);                                     \
    _Pragma("unroll")                                                 \
    for (int q = 0; q < 4; ++q) {                                     \
      g2lds16(A + aoff[q] + kk0_, &dA[q * 4096 + ldst]);              \
      g2lds16(Bm + boff[q] + kk0_, &dB[q * 4096 + ldst]);             \
    } } while (0)

#define PHASES256(sA, sB) do {                                                        \
    short8 af[4][2], bfr[4][2];                                                       \
    /* phase 0: read A mh0 + B nh0; MFMA i0..3 x j0..1 */                             \
    _Pragma("unroll") for (int kk = 0; kk < 2; ++kk) {                                \
      const int jb = ((kk * 4 + g4) ^ l7) * 8;                                        \
      _Pragma("unroll") for (int i = 0; i < 4; ++i)                                   \
        af[i][kk] = *(const short8*)&sA[(wr * 128 + i * 16 + r16) * 64 + jb];         \
      _Pragma("unroll") for (int j = 0; j < 2; ++j)                                   \
        bfr[j][kk] = *(const short8*)&sB[(wc * 64 + j * 16 + r16) * 64 + jb];         \
    }                                                                                 \
    __builtin_amdgcn_s_setprio(1);                                                    \
    _Pragma("unroll") for (int i = 0; i < 4; ++i)                                     \
    _Pragma("unroll") for (int j = 0; j < 2; ++j)                                     \
    _Pragma("unroll") for (int kk = 0; kk < 2; ++kk)                                  \
      acc[i][j] = __builtin_amdgcn_mfma_f32_16x16x32_bf16(af[i][kk], bfr[j][kk], acc[i][j], 0, 0, 0); \
    __builtin_amdgcn_s_setprio(0);                                                    \
    /* phase 1: read B nh1; MFMA i0..3 x j2..3 */                                     \
    _Pragma("unroll") for (int kk = 0; kk < 2; ++kk) {                                \
      const int jb = ((kk * 4 + g4) ^ l7) * 8;                                        \
      _Pragma("unroll") for (int j = 0; j < 2; ++j)                                   \
        bfr[2 + j][kk] = *(const short8*)&sB[(wc * 64 + (2 + j) * 16 + r16) * 64 + jb]; \
    }                                                                                 \
    __builtin_amdgcn_s_setprio(1);                                                    \
    _Pragma("unroll") for (int i = 0; i < 4; ++i)                                     \
    _Pragma("unroll") for (int j = 0; j < 2; ++j)                                     \
    _Pragma("unroll") for (int kk = 0; kk < 2; ++kk)                                  \
      acc[i][2 + j] = __builtin_amdgcn_mfma_f32_16x16x32_bf16(af[i][kk], bfr[2 + j][kk], acc[i][2 + j], 0, 0, 0); \
    __builtin_amdgcn_s_setprio(0);                                                    \
    /* phase 2: read A mh1; MFMA i4..7 x j2..3 */                                     \
    _Pragma("unroll") for (int kk = 0; kk < 2; ++kk) {                                \
      const int jb = ((kk * 4 + g4) ^ l7) * 8;                                        \
      _Pragma("unroll") for (int i = 0; i < 4; ++i)                                   \
        af[i][kk] = *(const short8*)&sA[(wr * 128 + (4 + i) * 16 + r16) * 64 + jb];   \
    }                                                                                 \
    __builtin_amdgcn_s_setprio(1);                                                    \
    _Pragma("unroll") for (int i = 0; i < 4; ++i)                                     \
    _Pragma("unroll") for (int j = 0; j < 2; ++j)                                     \
    _Pragma("unroll") for (int kk = 0; kk < 2; ++kk)                                  \
      acc[4 + i][2 + j] = __builtin_amdgcn_mfma_f32_16x16x32_bf16(af[i][kk], bfr[2 + j][kk], acc[4 + i][2 + j], 0, 0, 0); \
    __builtin_amdgcn_s_setprio(0);                                                    \
    /* phase 3: reuse A mh1 + B nh0; MFMA i4..7 x j0..1 */                            \
    __builtin_amdgcn_s_setprio(1);                                                    \
    _Pragma("unroll") for (int i = 0; i < 4; ++i)                                     \
    _Pragma("unroll") for (int j = 0; j < 2; ++j)                                     \
    _Pragma("unroll") for (int kk = 0; kk < 2; ++kk)                                  \
      acc[4 + i][j] = __builtin_amdgcn_mfma_f32_16x16x32_bf16(af[i][kk], bfr[j][kk], acc[4 + i][j], 0, 0, 0); \
    __builtin_amdgcn_s_setprio(0);                                                    \
  } while (0)

  STAGE256(0, lA0, lB0);
  for (int ktp = 0; ktp < (nK >> 1); ++ktp) {
    const int t1 = 2 * ktp + 1;
    __syncthreads();                       // drains tile 2*ktp loads (covered)
    STAGE256((long)t1 << 6, lA1, lB1);     // prefetch odd tile
    PHASES256(lA0, lB0);                   // compute even tile
    __syncthreads();                       // drains odd-tile loads (covered)
    if (t1 + 1 < nK) STAGE256((long)(t1 + 1) << 6, lA0, lB0);
    PHASES256(lA1, lB1);                   // compute odd tile
  }

#pragma unroll
  for (int j = 0; j < 4; ++j) {
    int col = n0 + wc * 64 + j * 16 + r16;
    float bv = bias[col];
#pragma unroll
    for (int i = 0; i < 8; ++i) {
      int rbase = m0 + wr * 128 + i * 16 + (g4 << 2);
#pragma unroll
      for (int r = 0; r < 4; ++r) {
        float o = fmaxf(acc[i][j][r] + bv, 0.f);
        C[(long)(rbase + r) * N + col] = f2bf(o);
      }
    }
  }
#undef STAGE256
#undef PHASES256
}

// ---------- 128x128 4-wave BK=64 static-dbuf GEMM (conv2 / fc / experts) ----------
__global__ __launch_bounds__(256, 2) void gemm128_bt_relu(
    const short* __restrict__ A, const short* __restrict__ Bm, short* __restrict__ C,
    const float* __restrict__ bias, int N, int K, int L, int S1, int S2, int nNB) {
  __shared__ __align__(16) short lA0[128 * 64], lA1[128 * 64];
  __shared__ __align__(16) short lB0[128 * 64], lB1[128 * 64];
  const int t = threadIdx.x, wave = t >> 6, lane = t & 63;
  const int wr = wave >> 1, wc = wave & 1;
  const int nwg = gridDim.x, qn = nwg >> 3, bid = blockIdx.x;
  const int swz = (bid & 7) * qn + (bid >> 3);
  const int m0 = (swz / nNB) * 128, n0 = (swz % nNB) * 128;
  const int arow = t >> 3;
  const int acolg = (((t & 7) ^ (arow & 7)) * 8);

  long aoff[4], boff[4];
#pragma unroll
  for (int qq = 0; qq < 4; ++qq) {
    int m = m0 + qq * 32 + arow;
    aoff[qq] = (long)(m / L) * S1 + (long)(m % L) * S2 + acolg;
    boff[qq] = (long)(n0 + qq * 32 + arow) * K + acolg;
  }
  const int ldst = wave * 512 + lane * 8;

  f32x4 acc[4][4];
#pragma unroll
  for (int i = 0; i < 4; ++i)
#pragma unroll
    for (int j = 0; j < 4; ++j) acc[i][j] = f32x4{0.f, 0.f, 0.f, 0.f};

  const int l7 = lane & 7, g4 = lane >> 4, r16 = lane & 15;
  const int nK = K >> 6;  // 24 / 36 / 16 here — all even

#define STAGE128(k0, dA, dB) do {                                     \
    const long kk0_ = (long)(k0);                                     \
    _Pragma("unroll")                                                 \
    for (int qq = 0; qq < 4; ++qq) {                                  \
      g2lds16(A + aoff[qq] + kk0_, &dA[qq * 2048 + ldst]);            \
      g2lds16(Bm + boff[qq] + kk0_, &dB[qq * 2048 + ldst]);           \
    } } while (0)

#define PHASES128(sA, sB) do {                                                        \
    _Pragma("unroll")                                                                 \
    for (int kk = 0; kk < 2; ++kk) {                                                  \
      const int jblk = ((kk * 4 + g4) ^ l7) * 8;                                      \
      short8 af[4], bfv[4];                                                           \
      _Pragma("unroll") for (int i = 0; i < 4; ++i)                                   \
        af[i] = *(const short8*)&sA[(wr * 64 + i * 16 + r16) * 64 + jblk];            \
      _Pragma("unroll") for (int j = 0; j < 4; ++j)                                   \
        bfv[j] = *(const short8*)&sB[(wc * 64 + j * 16 + r16) * 64 + jblk];           \
      __builtin_amdgcn_s_setprio(1);                                                  \
      _Pragma("unroll") for (int i = 0; i < 4; ++i)                                   \
      _Pragma("unroll") for (int j = 0; j < 4; ++j)                                   \
        acc[i][j] = __builtin_amdgcn_mfma_f32_16x16x32_bf16(af[i], bfv[j], acc[i][j], 0, 0, 0); \
      __builtin_amdgcn_s_setprio(0);                                                  \
    } } while (0)

  STAGE128(0, lA0, lB0);
  for (int ktp = 0; ktp < (nK >> 1); ++ktp) {
    const int t1 = 2 * ktp + 1;
    __syncthreads();                       // even tile ready (drain covered)
    STAGE128((long)t1 << 6, lA1, lB1);     // prefetch odd tile
    PHASES128(lA0, lB0);                   // compute even tile
    __syncthreads();                       // odd tile ready
    if (t1 + 1 < nK) STAGE128((long)(t1 + 1) << 6, lA0, lB0);
    PHASES128(lA1, lB1);                   // compute odd tile
  }

#pragma unroll
  for (int j = 0; j < 4; ++j) {
    int col = n0 + wc * 64 + j * 16 + r16;
    float bv = bias[col];
#pragma unroll
    for (int i = 0; i < 4; ++i) {
      int rbase = m0 + wr * 64 + i * 16 + (g4 << 2);
#pragma unroll
      for (int r = 0; r < 4; ++r) {
        float o = fmaxf(acc[i][j][r] + bv, 0.f);
        C[(long)(rbase + r) * N + col] = f2bf(o);
      }
    }
  }
#undef STAGE128
#undef PHASES128
}

// ---------- pool1 + fin-x1 dot (block per b): p1t + fin1p[b][2] ----------
__global__ __launch_bounds__(256) void pool1_fused(
    const short* __restrict__ x1t, short* __restrict__ p1t,
    const float* __restrict__ finw1, float* __restrict__ fin1p) {
  const int b = blockIdx.x, t = threadIdx.x, lane = t & 63, wave = t >> 6;
  const short* xb = x1t + (long)b * 15360;
  short* pb = p1t + (long)b * 9216;
  // pools: 18 x 128 short4 items
  for (int i = t; i < 2304; i += 256) {
    int c4 = i & 127, jp = i >> 7;
    short4v v = {0, 0, 0, 0};
    if (jp >= 1 && jp <= 16) {
      int j = jp - 1, l0 = 2 * j - 1, l1 = 2 * j;
      short4v a = (l0 >= 0) ? *(const short4v*)&xb[l0 * 512 + c4 * 4] : short4v{0, 0, 0, 0};
      short4v bb = (l1 < 30) ? *(const short4v*)&xb[l1 * 512 + c4 * 4] : short4v{0, 0, 0, 0};
#pragma unroll
      for (int u = 0; u < 4; ++u) v[u] = f2bf(fmaxf(bf2f(a[u]), bf2f(bb[u])));
    }
    *(short4v*)&pb[i * 4] = v;
  }
  // fin dot over x1t[b] (15360 elems), L2-hot
  float f0 = 0.f, f1 = 0.f;
#pragma unroll
  for (int it = 0; it < 15; ++it) {
    int i = (it * 256 + t) * 4;
    short4v xv = *(const short4v*)&xb[i];
    float4 w0 = *(const float4*)&finw1[i];
    float4 w1 = *(const float4*)&finw1[15360 + i];
    float a0 = bf2f(xv[0]), a1 = bf2f(xv[1]), a2 = bf2f(xv[2]), a3 = bf2f(xv[3]);
    f0 += a0 * w0.x + a1 * w0.y + a2 * w0.z + a3 * w0.w;
    f1 += a0 * w1.x + a1 * w1.y + a2 * w1.z + a3 * w1.w;
  }
#pragma unroll
  for (int off = 32; off > 0; off >>= 1) {
    f0 += __shfl_down(f0, off);
    f1 += __shfl_down(f1, off);
  }
  __shared__ float red[4][2];
  if (lane == 0) { red[wave][0] = f0; red[wave][1] = f1; }
  __syncthreads();
  if (t == 0) {
    float F0 = red[0][0] + red[1][0] + red[2][0] + red[3][0];
    float F1 = red[0][1] + red[1][1] + red[2][1] + red[3][1];
    fin1p[b * 2 + 0] = F0;
    fin1p[b * 2 + 1] = F1;
  }
}

// ---------- pool2 + fin-x2 dot (block per b): p2t + fin2p[b][2] ----------
__global__ __launch_bounds__(256) void pool2_fused(
    const short* __restrict__ x2t, short* __restrict__ p2t,
    const float* __restrict__ finw2, float* __restrict__ fin2p) {
  const int b = blockIdx.x, t = threadIdx.x, lane = t & 63, wave = t >> 6;
  const short* xb = x2t + (long)b * 4096;
  short* pb = p2t + (long)b * 2304;
  // pools: 9 x 64 short4 items
  for (int i = t; i < 576; i += 256) {
    int c4 = i & 63, j = i >> 6;
    int l0 = 2 * j - 1, l1 = 2 * j;
    short4v a = (l0 >= 0) ? *(const short4v*)&xb[l0 * 256 + c4 * 4] : short4v{0, 0, 0, 0};
    short4v bb = (l1 < 16) ? *(const short4v*)&xb[l1 * 256 + c4 * 4] : short4v{0, 0, 0, 0};
    short4v v;
#pragma unroll
    for (int u = 0; u < 4; ++u) v[u] = f2bf(fmaxf(bf2f(a[u]), bf2f(bb[u])));
    *(short4v*)&pb[i * 4] = v;
  }
  // fin dot over x2t[b] (4096 elems)
  float f0 = 0.f, f1 = 0.f;
#pragma unroll
  for (int it = 0; it < 4; ++it) {
    int i = (it * 256 + t) * 4;
    short4v xv = *(const short4v*)&xb[i];
    float4 w0 = *(const float4*)&finw2[i];
    float4 w1 = *(const float4*)&finw2[4096 + i];
    float a0 = bf2f(xv[0]), a1 = bf2f(xv[1]), a2 = bf2f(xv[2]), a3 = bf2f(xv[3]);
    f0 += a0 * w0.x + a1 * w0.y + a2 * w0.z + a3 * w0.w;
    f1 += a0 * w1.x + a1 * w1.y + a2 * w1.z + a3 * w1.w;
  }
#pragma unroll
  for (int off = 32; off > 0; off >>= 1) {
    f0 += __shfl_down(f0, off);
    f1 += __shfl_down(f1, off);
  }
  __shared__ float red[4][2];
  if (lane == 0) { red[wave][0] = f0; red[wave][1] = f1; }
  __syncthreads();
  if (t == 0) {
    fin2p[b * 2 + 0] = red[0][0] + red[1][0] + red[2][0] + red[3][0];
    fin2p[b * 2 + 1] = red[0][1] + red[1][1] + red[2][1] + red[3][1];
  }
}

// ---------- final (slim): expert select + agg fold + partials -> out [B,2] ----------
__global__ __launch_bounds__(64) void final_k(
    const short* __restrict__ h, const int* __restrict__ eidx,
    const float* __restrict__ e_w2, const float* __restrict__ e_b2,
    const float* __restrict__ agg_w, const float* __restrict__ agg_b,
    const float* __restrict__ fin_w, const float* __restrict__ fin_b,
    const float* __restrict__ fin1p, const float* __restrict__ fin2p,
    float* __restrict__ out) {
  const int b = blockIdx.x, lane = threadIdx.x;
  const int e = eidx[b];
  const short* hp = h + (long)b * 4096 + e * 512;
  const float* w20 = e_w2 + (e * 2 + 0) * 512;
  const float* w21 = e_w2 + (e * 2 + 1) * 512;
  float s0 = 0.f, s1 = 0.f;
#pragma unroll
  for (int it = 0; it < 8; ++it) {
    int i = it * 64 + lane;
    float hv = bf2f(hp[i]);
    s0 += hv * w20[i];
    s1 += hv * w21[i];
  }
#pragma unroll
  for (int off = 32; off > 0; off >>= 1) {
    s0 += __shfl_down(s0, off);
    s1 += __shfl_down(s1, off);
  }
  if (lane == 0) {
    float sel0 = s0 + e_b2[e * 2 + 0];
    float sel1 = s1 + e_b2[e * 2 + 1];
    float agg0 = sel0 * agg_w[e * 2] + sel1 * agg_w[e * 2 + 1] + agg_b[0];
    float agg1 = sel0 * agg_w[16 + e * 2] + sel1 * agg_w[16 + e * 2 + 1] + agg_b[1];
    float F0 = fin1p[b * 2 + 0] + fin2p[b * 2 + 0];
    float F1 = fin1p[b * 2 + 1] + fin2p[b * 2 + 1];
    out[b * 2 + 0] = F0 + agg0 * fin_w[0] + agg1 * fin_w[1] + fin_b[0];
    out[b * 2 + 1] = F1 + agg0 * fin_w[19458 + 0] + agg1 * fin_w[19458 + 1] + fin_b[1];
  }
}

// ---------- launch ----------
extern "C" void kernel_launch(void* const* d_in, const int* in_sizes, int n_in,
                              void* d_out, int out_size, void* d_ws, size_t ws_size,
                              hipStream_t stream) {
  const float* x       = (const float*)d_in[0];
  const int*   eidx    = (const int*)d_in[1];
  const float* conv1_w = (const float*)d_in[2];
  const float* conv1_b = (const float*)d_in[3];
  const float* conv2_w = (const float*)d_in[4];
  const float* conv2_b = (const float*)d_in[5];
  const float* fc_w    = (const float*)d_in[6];
  const float* fc_b    = (const float*)d_in[7];
  const float* e_w1    = (const float*)d_in[8];
  const float* e_b1    = (const float*)d_in[9];
  const float* e_w2    = (const float*)d_in[10];
  const float* e_b2    = (const float*)d_in[11];
  const float* agg_w   = (const float*)d_in[12];
  const float* agg_b   = (const float*)d_in[13];
  const float* fin_w   = (const float*)d_in[14];
  const float* fin_b   = (const float*)d_in[15];
  float* out = (float*)d_out;

  char* ws = (char*)d_ws;
  short* xt    = (short*)(ws + 0L);          // 134,217,728
  short* x1t   = (short*)(ws + 134217728L);  //  62,914,560
  short* p1t   = (short*)(ws + 197132288L);  //  37,748,736
  short* x2t   = (short*)(ws + 234881024L);  //  16,777,216
  short* p2t   = (short*)(ws + 251658240L);  //   9,437,184
  short* sf    = (short*)(ws + 261095424L);  //   4,194,304
  short* h     = (short*)(ws + 265289728L);  //  16,777,216
  short* w1t   = (short*)(ws + 282066944L);  //   3,145,728
  short* w2t   = (short*)(ws + 285212672L);  //     786,432
  short* fcwt  = (short*)(ws + 285999104L);  //   4,718,592
  short* ew1t  = (short*)(ws + 290717696L);  //   8,388,608
  float* finw1 = (float*)(ws + 299106304L);  //     122,880
  float* finw2 = (float*)(ws + 299229184L);  //      32,768  -> total 299,261,952 B
  // fin partials alias the xt region (xt dead after conv1; pools run later)
  float* fin1p = (float*)(ws + 0L);          //      16,384
  float* fin2p = (float*)(ws + 16384L);      //      16,384

  prep_weights<<<4096, 256, 0, stream>>>(conv1_w, conv2_w, fc_w, e_w1, fin_w,
                                         w1t, w2t, fcwt, ew1t, finw1, finw2);
  prep_x<<<dim3(2048, 16), 256, 0, stream>>>(x, xt);
  // conv1: M=61440 N=512 K=3072; 256^2 tiles -> grid 240m x 2n = 480 (480%8==0)
  gemm256_bt_relu<<<480, 512, 0, stream>>>(xt, w1t, x1t, conv1_b, 512, 3072, 30, 32768, 1024, 2);
  pool1_fused<<<2048, 256, 0, stream>>>(x1t, p1t, finw1, fin1p);
  // conv2: M=32768 N=256 K=1536, rows = p1t[(b*18+j)*512]; grid 256m x 2n = 512
  gemm128_bt_relu<<<512, 256, 0, stream>>>(p1t, w2t, x2t, conv2_b, 256, 1536, 16, 9216, 512, 2);
  pool2_fused<<<2048, 256, 0, stream>>>(x2t, p2t, finw2, fin2p);
  // fc: M=2048 N=1024 K=2304; grid 16m x 8n = 128
  gemm128_bt_relu<<<128, 256, 0, stream>>>(p2t, fcwt, sf, fc_b, 1024, 2304, 1, 2304, 0, 8);
  // experts dense: M=2048 N=4096 K=1024; grid 16m x 32n = 512
  gemm128_bt_relu<<<512, 256, 0, stream>>>(sf, ew1t, h, e_b1, 4096, 1024, 1, 1024, 0, 32);
  final_k<<<2048, 64, 0, stream>>>(h, eidx, e_w2, e_b2, agg_w, agg_b,
                                   fin_w, fin_b, fin1p, fin2p, out);
}